// Round 2
// baseline (31172.974 us; speedup 1.0000x reference)
//
#include <hip/hip_runtime.h>
#include <cstdint>
#include <cstddef>

#define NB 32
#define NT 2048
#define ND 256
#define NH 256
#define NG 1024   // 4*H
#define ROWS 16   // bt-rows per block in zx_kernel

#define TPB 512
#define KREG 96   // packed bf16 pairs per column held in regs (k = 64..255)
#define GLDS 16   // uint2 groups in LDS (k = 0..63): lw[GLDS][NG] = 128 KB

__device__ __forceinline__ float sigf(float x) {
    return 1.0f / (1.0f + __expf(-x));
}
__device__ __forceinline__ float tanh_fast(float x) {
    return 2.0f / (1.0f + __expf(-2.0f * x)) - 1.0f;
}

// bf16 round-to-nearest-even, result in low 16 bits
__device__ __forceinline__ uint32_t bf16_rtne(float f) {
    uint32_t u = __float_as_uint(f);
    return (u + 0x7FFFu + ((u >> 16) & 1u)) >> 16;
}
__device__ __forceinline__ uint32_t pack2(float f0, float f1) {
    return bf16_rtne(f0) | (bf16_rtne(f1) << 16);
}
// unpack: low half -> k, high half -> k+1 (bf16 -> f32 is a shift / mask)
__device__ __forceinline__ float blo(uint32_t w) { return __uint_as_float(w << 16); }
__device__ __forceinline__ float bhi(uint32_t w) { return __uint_as_float(w & 0xFFFF0000u); }

// ---------------------------------------------------------------------------
// Phase 1: ZX[bt][j] = sum_k X[bt][k] * Wi[k][j] + bias[j]   (unchanged, ~0.3 ms)
__global__ __launch_bounds__(256) void zx_kernel(const float* __restrict__ X,
                                                 const float* __restrict__ Wi,
                                                 const float* __restrict__ bias,
                                                 float* __restrict__ ZX) {
    __shared__ float xs[ROWS][ND];
    const int tid = threadIdx.x;
    const size_t row0 = (size_t)blockIdx.x * ROWS;

    const float4* Xv = (const float4*)(X + row0 * ND);
    float4* xsv = (float4*)(&xs[0][0]);
#pragma unroll
    for (int i = 0; i < (ROWS * ND / 4) / 256; ++i)
        xsv[tid + i * 256] = Xv[tid + i * 256];
    __syncthreads();

    const int j0 = tid * 4;
    const float4 bv = *(const float4*)(bias + j0);
    float acc[ROWS][4];
#pragma unroll
    for (int r = 0; r < ROWS; ++r) {
        acc[r][0] = bv.x; acc[r][1] = bv.y; acc[r][2] = bv.z; acc[r][3] = bv.w;
    }

    for (int k = 0; k < ND; ++k) {
        const float4 w = *(const float4*)(Wi + (size_t)k * NG + j0);
#pragma unroll
        for (int r = 0; r < ROWS; ++r) {
            const float x = xs[r][k];
            acc[r][0] = fmaf(x, w.x, acc[r][0]);
            acc[r][1] = fmaf(x, w.y, acc[r][1]);
            acc[r][2] = fmaf(x, w.z, acc[r][2]);
            acc[r][3] = fmaf(x, w.w, acc[r][3]);
        }
    }

#pragma unroll
    for (int r = 0; r < ROWS; ++r) {
        float4 o;
        o.x = acc[r][0]; o.y = acc[r][1]; o.z = acc[r][2]; o.w = acc[r][3];
        *(float4*)(ZX + (row0 + r) * NG + j0) = o;
    }
}

// ---------------------------------------------------------------------------
// Phase 2: persistent-weight recurrence. One block per batch, 512 threads.
// Thread owns gate columns {tid, tid+512}. Wh (bf16-packed) lives in
// 192 VGPRs/thread (k=64..255) + 128 KB LDS (k=0..63) for the whole kernel.
__global__ __launch_bounds__(TPB, 2) void rec_pers(
    const float* __restrict__ ZX,
    const float* __restrict__ Wh,
    const int* __restrict__ lengths,
    float* __restrict__ out)
{
    __shared__ uint2 lw[GLDS][NG];            // 128 KB: k=0..63, 4 k per uint2
    __shared__ __align__(16) float hs[NH];    // current hidden state (f32)
    __shared__ float zs[NG];                  // pre-activations this step

    const int b   = blockIdx.x;
    const int tid = threadIdx.x;
    const int j0  = tid;
    const int j1  = tid + 512;

    // ---- one-time weight staging (coalesced over j at fixed k) ----
#pragma unroll 4
    for (int g = 0; g < GLDS; ++g) {
        const int k = g * 4;
        uint2 p;
        p.x = pack2(Wh[(size_t)(k + 0) * NG + j0], Wh[(size_t)(k + 1) * NG + j0]);
        p.y = pack2(Wh[(size_t)(k + 2) * NG + j0], Wh[(size_t)(k + 3) * NG + j0]);
        lw[g][j0] = p;
        p.x = pack2(Wh[(size_t)(k + 0) * NG + j1], Wh[(size_t)(k + 1) * NG + j1]);
        p.y = pack2(Wh[(size_t)(k + 2) * NG + j1], Wh[(size_t)(k + 3) * NG + j1]);
        lw[g][j1] = p;
    }

    uint32_t w0[KREG], w1[KREG];
#pragma unroll
    for (int kk = 0; kk < KREG; ++kk) {
        const int k = 64 + kk * 2;
        w0[kk] = pack2(Wh[(size_t)k * NG + j0], Wh[(size_t)(k + 1) * NG + j0]);
        w1[kk] = pack2(Wh[(size_t)k * NG + j1], Wh[(size_t)(k + 1) * NG + j1]);
    }

    if (tid < NH) hs[tid] = 0.0f;
    float c = 0.0f;
    __syncthreads();

    const int len   = lengths[b];
    const int steps = (len < 1) ? 1 : len;    // idx = max(0, len-1) -> run idx+1 steps

    for (int t = 0; t < steps; ++t) {
        // issue early; consumed only at the end of the step (hides L3/HBM latency)
        const float z0 = ZX[((size_t)b * NT + t) * NG + j0];
        const float z1 = ZX[((size_t)b * NT + t) * NG + j1];

        float a0 = 0.0f, a1 = 0.0f, a2 = 0.0f, a3 = 0.0f;

        // k = 0..63 from LDS weights
#pragma unroll
        for (int g = 0; g < GLDS; ++g) {
            const float4 h4 = *(const float4*)(hs + g * 4);   // broadcast
            const uint2 pa = lw[g][j0];
            const uint2 pb = lw[g][j1];
            a0 = fmaf(h4.x, blo(pa.x), a0); a2 = fmaf(h4.y, bhi(pa.x), a2);
            a0 = fmaf(h4.z, blo(pa.y), a0); a2 = fmaf(h4.w, bhi(pa.y), a2);
            a1 = fmaf(h4.x, blo(pb.x), a1); a3 = fmaf(h4.y, bhi(pb.x), a3);
            a1 = fmaf(h4.z, blo(pb.y), a1); a3 = fmaf(h4.w, bhi(pb.y), a3);
        }

        // k = 64..255 from register-resident weights
#pragma unroll
        for (int q = 0; q < KREG / 2; ++q) {
            const float4 h4 = *(const float4*)(hs + 64 + q * 4);  // broadcast
            const uint32_t pa0 = w0[2 * q], pa1 = w0[2 * q + 1];
            const uint32_t pb0 = w1[2 * q], pb1 = w1[2 * q + 1];
            a0 = fmaf(h4.x, blo(pa0), a0); a2 = fmaf(h4.y, bhi(pa0), a2);
            a0 = fmaf(h4.z, blo(pa1), a0); a2 = fmaf(h4.w, bhi(pa1), a2);
            a1 = fmaf(h4.x, blo(pb0), a1); a3 = fmaf(h4.y, bhi(pb0), a3);
            a1 = fmaf(h4.z, blo(pb1), a1); a3 = fmaf(h4.w, bhi(pb1), a3);
        }

        zs[j0] = z0 + a0 + a2;
        zs[j1] = z1 + a1 + a3;
        __syncthreads();

        if (tid < NH) {
            const float iv = zs[tid];
            const float fv = zs[NH + tid];
            const float gv = zs[2 * NH + tid];
            const float ov = zs[3 * NH + tid];
            c = sigf(fv) * c + sigf(iv) * tanh_fast(gv);
            hs[tid] = sigf(ov) * tanh_fast(c);
        }
        __syncthreads();
    }

    if (tid < NH) out[(size_t)b * NH + tid] = hs[tid];
}

// ---------------------------------------------------------------------------
// Fallback recurrence (streams weights; used only if ws can't hold ZX)
__global__ __launch_bounds__(512) void rec_fallback(
    const float* __restrict__ X,
    const float* __restrict__ Wi,
    const float* __restrict__ Wh,
    const float* __restrict__ bias,
    const int* __restrict__ lengths,
    float* __restrict__ out)
{
    __shared__ float hs[NH];
    __shared__ float zs[NG];
    __shared__ float xs[ND];

    const int b   = blockIdx.x;
    const int tid = threadIdx.x;
    const int c0  = tid * 2;

    const int len   = lengths[b];
    const int steps = (len < 1) ? 1 : len;

    float c_state = 0.0f;
    if (tid < NH) hs[tid] = 0.0f;
    const float b0 = bias[c0], b1 = bias[c0 + 1];
    __syncthreads();

    for (int t = 0; t < steps; ++t) {
        float a0 = b0, a1 = b1;
        if (tid < ND) xs[tid] = X[((size_t)b * NT + t) * ND + tid];
        __syncthreads();
#pragma unroll 2
        for (int k = 0; k < ND; k += 4) {
            const float4 xv = *(const float4*)(xs + k);
            const float2 w0 = *(const float2*)(Wi + (size_t)(k + 0) * NG + c0);
            const float2 w1 = *(const float2*)(Wi + (size_t)(k + 1) * NG + c0);
            const float2 w2 = *(const float2*)(Wi + (size_t)(k + 2) * NG + c0);
            const float2 w3 = *(const float2*)(Wi + (size_t)(k + 3) * NG + c0);
            a0 = fmaf(xv.x, w0.x, a0); a1 = fmaf(xv.x, w0.y, a1);
            a0 = fmaf(xv.y, w1.x, a0); a1 = fmaf(xv.y, w1.y, a1);
            a0 = fmaf(xv.z, w2.x, a0); a1 = fmaf(xv.z, w2.y, a1);
            a0 = fmaf(xv.w, w3.x, a0); a1 = fmaf(xv.w, w3.y, a1);
        }
#pragma unroll 2
        for (int k = 0; k < NH; k += 4) {
            const float4 hv = *(const float4*)(hs + k);
            const float2 w0 = *(const float2*)(Wh + (size_t)(k + 0) * NG + c0);
            const float2 w1 = *(const float2*)(Wh + (size_t)(k + 1) * NG + c0);
            const float2 w2 = *(const float2*)(Wh + (size_t)(k + 2) * NG + c0);
            const float2 w3 = *(const float2*)(Wh + (size_t)(k + 3) * NG + c0);
            a0 = fmaf(hv.x, w0.x, a0); a1 = fmaf(hv.x, w0.y, a1);
            a0 = fmaf(hv.y, w1.x, a0); a1 = fmaf(hv.y, w1.y, a1);
            a0 = fmaf(hv.z, w2.x, a0); a1 = fmaf(hv.z, w2.y, a1);
            a0 = fmaf(hv.w, w3.x, a0); a1 = fmaf(hv.w, w3.y, a1);
        }

        float2 zo; zo.x = a0; zo.y = a1;
        *(float2*)(zs + c0) = zo;
        __syncthreads();

        if (tid < NH) {
            const float iv = zs[tid];
            const float fv = zs[NH + tid];
            const float gv = zs[2 * NH + tid];
            const float ov = zs[3 * NH + tid];
            c_state = sigf(fv) * c_state + sigf(iv) * tanh_fast(gv);
            hs[tid] = sigf(ov) * tanh_fast(c_state);
        }
        __syncthreads();
    }

    if (tid < NH) out[(size_t)b * NH + tid] = hs[tid];
}

extern "C" void kernel_launch(void* const* d_in, const int* in_sizes, int n_in,
                              void* d_out, int out_size, void* d_ws, size_t ws_size,
                              hipStream_t stream) {
    const float* X       = (const float*)d_in[0];
    const int*   lengths = (const int*)d_in[1];
    const float* Wi      = (const float*)d_in[2];
    const float* Wh      = (const float*)d_in[3];
    const float* bias    = (const float*)d_in[4];
    float* out = (float*)d_out;

    const size_t zx_bytes = (size_t)NB * NT * NG * sizeof(float);  // 256 MB
    float* ZX = (float*)d_ws;

    if (ws_size >= zx_bytes) {
        zx_kernel<<<dim3((NB * NT) / ROWS), dim3(256), 0, stream>>>(X, Wi, bias, ZX);
        rec_pers<<<dim3(NB), dim3(TPB), 0, stream>>>(ZX, Wh, lengths, out);
    } else {
        rec_fallback<<<dim3(NB), dim3(512), 0, stream>>>(X, Wi, Wh, bias, lengths, out);
    }
}

// Round 3
// 4002.572 us; speedup vs baseline: 7.7882x; 7.7882x over previous
//
#include <hip/hip_runtime.h>
#include <cstdint>
#include <cstddef>

#define NB 32
#define NT 2048
#define ND 256
#define NH 256
#define NG 1024   // 4*H
#define ROWS 16   // bt-rows per block in zx_kernel

#define TPB 512
#define KLDS 72            // k-values with weights in LDS (18 uint2 rows)
#define NQR  92            // f16 packs per column in regs: (256-72)/2

typedef _Float16 h2_t __attribute__((ext_vector_type(2)));

__device__ __forceinline__ float sigf(float x) {
    return 1.0f / (1.0f + __expf(-x));
}
__device__ __forceinline__ float tanh_fast(float x) {
    return 2.0f / (1.0f + __expf(-2.0f * x)) - 1.0f;
}

__device__ __forceinline__ h2_t as_h2(uint32_t u) {
    union { uint32_t u; h2_t h; } c; c.u = u; return c.h;
}
__device__ __forceinline__ uint32_t packf16(float a, float b) {
    union { uint32_t u; h2_t h; } c;
    c.h[0] = (_Float16)a; c.h[1] = (_Float16)b;
    return c.u;
}
__device__ __forceinline__ float dot2(uint32_t hpack, uint32_t wpack, float acc) {
    return __builtin_amdgcn_fdot2(as_h2(hpack), as_h2(wpack), acc, false);
}

// ---------------------------------------------------------------------------
// Phase 1: ZX[bt][j] = sum_k X[bt][k] * Wi[k][j] + bias[j]
__global__ __launch_bounds__(256) void zx_kernel(const float* __restrict__ X,
                                                 const float* __restrict__ Wi,
                                                 const float* __restrict__ bias,
                                                 float* __restrict__ ZX) {
    __shared__ float xs[ROWS][ND];
    const int tid = threadIdx.x;
    const size_t row0 = (size_t)blockIdx.x * ROWS;

    const float4* Xv = (const float4*)(X + row0 * ND);
    float4* xsv = (float4*)(&xs[0][0]);
#pragma unroll
    for (int i = 0; i < (ROWS * ND / 4) / 256; ++i)
        xsv[tid + i * 256] = Xv[tid + i * 256];
    __syncthreads();

    const int j0 = tid * 4;
    const float4 bv = *(const float4*)(bias + j0);
    float acc[ROWS][4];
#pragma unroll
    for (int r = 0; r < ROWS; ++r) {
        acc[r][0] = bv.x; acc[r][1] = bv.y; acc[r][2] = bv.z; acc[r][3] = bv.w;
    }

    for (int k = 0; k < ND; ++k) {
        const float4 w = *(const float4*)(Wi + (size_t)k * NG + j0);
#pragma unroll
        for (int r = 0; r < ROWS; ++r) {
            const float x = xs[r][k];
            acc[r][0] = fmaf(x, w.x, acc[r][0]);
            acc[r][1] = fmaf(x, w.y, acc[r][1]);
            acc[r][2] = fmaf(x, w.z, acc[r][2]);
            acc[r][3] = fmaf(x, w.w, acc[r][3]);
        }
    }

#pragma unroll
    for (int r = 0; r < ROWS; ++r) {
        float4 o;
        o.x = acc[r][0]; o.y = acc[r][1]; o.z = acc[r][2]; o.w = acc[r][3];
        *(float4*)(ZX + (row0 + r) * NG + j0) = o;
    }
}

// ---------------------------------------------------------------------------
// Phase 2: persistent-weight recurrence. One block per batch, 512 threads.
// Thread owns gate columns {tid, tid+512}. Wh as packed f16 pairs:
// k=0..71 in LDS (144 KB), k=72..255 in 184 VGPRs/thread. v_dot2_f32_f16 math.
// LDS-limited to 1 block/CU (8 waves = 2/EU); waves_per_eu(2,2) pins the
// register allocator at the matching 256-VGPR budget so weights stay resident.
__global__ __launch_bounds__(TPB)
__attribute__((amdgpu_waves_per_eu(2, 2)))
void rec_pers(
    const float* __restrict__ ZX,
    const float* __restrict__ Wh,
    const int* __restrict__ lengths,
    float* __restrict__ out)
{
    __shared__ uint2 lw[KLDS / 4][NG];            // 144 KB: row r = k 4r..4r+3
    __shared__ float zs[NG];                      // 4 KB pre-activations
    __shared__ __align__(16) _Float16 hs_h[NH];   // 512 B hidden state, f16

    const int b   = blockIdx.x;
    const int tid = threadIdx.x;
    const int j0  = tid;
    const int j1  = tid + 512;

    // ---- one-time weight staging (coalesced over j at fixed k) ----
#pragma unroll 2
    for (int r = 0; r < KLDS / 4; ++r) {
        const int k = r * 4;
        uint2 p;
        p.x = packf16(Wh[(size_t)(k + 0) * NG + j0], Wh[(size_t)(k + 1) * NG + j0]);
        p.y = packf16(Wh[(size_t)(k + 2) * NG + j0], Wh[(size_t)(k + 3) * NG + j0]);
        lw[r][j0] = p;
        p.x = packf16(Wh[(size_t)(k + 0) * NG + j1], Wh[(size_t)(k + 1) * NG + j1]);
        p.y = packf16(Wh[(size_t)(k + 2) * NG + j1], Wh[(size_t)(k + 3) * NG + j1]);
        lw[r][j1] = p;
    }

    uint32_t wa[NQR], wb[NQR];
#pragma unroll
    for (int q = 0; q < NQR; ++q) {
        const int k = KLDS + 2 * q;
        wa[q] = packf16(Wh[(size_t)k * NG + j0], Wh[(size_t)(k + 1) * NG + j0]);
        wb[q] = packf16(Wh[(size_t)k * NG + j1], Wh[(size_t)(k + 1) * NG + j1]);
    }

    if (tid < NH) hs_h[tid] = (_Float16)0.0f;
    float c = 0.0f;
    __syncthreads();

    const int len   = lengths[b];
    const int steps = (len < 1) ? 1 : len;    // idx = max(0, len-1) -> idx+1 steps

    for (int t = 0; t < steps; ++t) {
        // issue early; consumed only at zs write (hides L3/HBM latency)
        const float z0 = ZX[((size_t)b * NT + t) * NG + j0];
        const float z1 = ZX[((size_t)b * NT + t) * NG + j1];

        float a0 = 0.0f, a1 = 0.0f, a2 = 0.0f, a3 = 0.0f;

        // k = 0..71: weights from LDS (stride-8B lane reads: conflict-free)
#pragma unroll
        for (int r = 0; r < KLDS / 4; ++r) {
            const uint2 ha = *(const uint2*)(hs_h + 4 * r);   // broadcast
            const uint2 pa = lw[r][j0];
            const uint2 pb = lw[r][j1];
            a0 = dot2(ha.x, pa.x, a0); a2 = dot2(ha.y, pa.y, a2);
            a1 = dot2(ha.x, pb.x, a1); a3 = dot2(ha.y, pb.y, a3);
        }

        // k = 72..255: register-resident weights
#pragma unroll
        for (int q = 0; q < NQR; q += 2) {
            const uint2 hu = *(const uint2*)(hs_h + KLDS + 2 * q);  // broadcast
            a0 = dot2(hu.x, wa[q], a0);     a2 = dot2(hu.y, wa[q + 1], a2);
            a1 = dot2(hu.x, wb[q], a1);     a3 = dot2(hu.y, wb[q + 1], a3);
        }

        zs[j0] = z0 + a0 + a2;
        zs[j1] = z1 + a1 + a3;
        __syncthreads();

        if (tid < NH) {
            const float iv = zs[tid];
            const float fv = zs[NH + tid];
            const float gv = zs[2 * NH + tid];
            const float ov = zs[3 * NH + tid];
            c = sigf(fv) * c + sigf(iv) * tanh_fast(gv);
            hs_h[tid] = (_Float16)(sigf(ov) * tanh_fast(c));
        }
        __syncthreads();
    }

    if (tid < NH) {
        // recompute final h in f32 from last zs for output precision
        const float ov = zs[3 * NH + tid];
        out[(size_t)b * NH + tid] = sigf(ov) * tanh_fast(c);
    }
}

// ---------------------------------------------------------------------------
// Fallback recurrence (streams weights; used only if ws can't hold ZX)
__global__ __launch_bounds__(512) void rec_fallback(
    const float* __restrict__ X,
    const float* __restrict__ Wi,
    const float* __restrict__ Wh,
    const float* __restrict__ bias,
    const int* __restrict__ lengths,
    float* __restrict__ out)
{
    __shared__ float hs[NH];
    __shared__ float zs[NG];
    __shared__ float xs[ND];

    const int b   = blockIdx.x;
    const int tid = threadIdx.x;
    const int c0  = tid * 2;

    const int len   = lengths[b];
    const int steps = (len < 1) ? 1 : len;

    float c_state = 0.0f;
    if (tid < NH) hs[tid] = 0.0f;
    const float b0 = bias[c0], b1 = bias[c0 + 1];
    __syncthreads();

    for (int t = 0; t < steps; ++t) {
        float a0 = b0, a1 = b1;
        if (tid < ND) xs[tid] = X[((size_t)b * NT + t) * ND + tid];
        __syncthreads();
#pragma unroll 2
        for (int k = 0; k < ND; k += 4) {
            const float4 xv = *(const float4*)(xs + k);
            const float2 w0 = *(const float2*)(Wi + (size_t)(k + 0) * NG + c0);
            const float2 w1 = *(const float2*)(Wi + (size_t)(k + 1) * NG + c0);
            const float2 w2 = *(const float2*)(Wi + (size_t)(k + 2) * NG + c0);
            const float2 w3 = *(const float2*)(Wi + (size_t)(k + 3) * NG + c0);
            a0 = fmaf(xv.x, w0.x, a0); a1 = fmaf(xv.x, w0.y, a1);
            a0 = fmaf(xv.y, w1.x, a0); a1 = fmaf(xv.y, w1.y, a1);
            a0 = fmaf(xv.z, w2.x, a0); a1 = fmaf(xv.z, w2.y, a1);
            a0 = fmaf(xv.w, w3.x, a0); a1 = fmaf(xv.w, w3.y, a1);
        }
#pragma unroll 2
        for (int k = 0; k < NH; k += 4) {
            const float4 hv = *(const float4*)(hs + k);
            const float2 w0 = *(const float2*)(Wh + (size_t)(k + 0) * NG + c0);
            const float2 w1 = *(const float2*)(Wh + (size_t)(k + 1) * NG + c0);
            const float2 w2 = *(const float2*)(Wh + (size_t)(k + 2) * NG + c0);
            const float2 w3 = *(const float2*)(Wh + (size_t)(k + 3) * NG + c0);
            a0 = fmaf(hv.x, w0.x, a0); a1 = fmaf(hv.x, w0.y, a1);
            a0 = fmaf(hv.y, w1.x, a0); a1 = fmaf(hv.y, w1.y, a1);
            a0 = fmaf(hv.z, w2.x, a0); a1 = fmaf(hv.z, w2.y, a1);
            a0 = fmaf(hv.w, w3.x, a0); a1 = fmaf(hv.w, w3.y, a1);
        }

        float2 zo; zo.x = a0; zo.y = a1;
        *(float2*)(zs + c0) = zo;
        __syncthreads();

        if (tid < NH) {
            const float iv = zs[tid];
            const float fv = zs[NH + tid];
            const float gv = zs[2 * NH + tid];
            const float ov = zs[3 * NH + tid];
            c_state = sigf(fv) * c_state + sigf(iv) * tanh_fast(gv);
            hs[tid] = sigf(ov) * tanh_fast(c_state);
        }
        __syncthreads();
    }

    if (tid < NH) out[(size_t)b * NH + tid] = hs[tid];
}

extern "C" void kernel_launch(void* const* d_in, const int* in_sizes, int n_in,
                              void* d_out, int out_size, void* d_ws, size_t ws_size,
                              hipStream_t stream) {
    const float* X       = (const float*)d_in[0];
    const int*   lengths = (const int*)d_in[1];
    const float* Wi      = (const float*)d_in[2];
    const float* Wh      = (const float*)d_in[3];
    const float* bias    = (const float*)d_in[4];
    float* out = (float*)d_out;

    const size_t zx_bytes = (size_t)NB * NT * NG * sizeof(float);  // 256 MB
    float* ZX = (float*)d_ws;

    if (ws_size >= zx_bytes) {
        zx_kernel<<<dim3((NB * NT) / ROWS), dim3(256), 0, stream>>>(X, Wi, bias, ZX);
        rec_pers<<<dim3(NB), dim3(TPB), 0, stream>>>(ZX, Wh, lengths, out);
    } else {
        rec_fallback<<<dim3(NB), dim3(512), 0, stream>>>(X, Wi, Wh, bias, lengths, out);
    }
}